// Round 8
// baseline (375.550 us; speedup 1.0000x reference)
//
#include <hip/hip_runtime.h>

constexpr int NB = 32;    // batch
constexpr int NS = 4096;  // sequence
constexpr int ND = 512;   // feature dim

// e = exp(tanh(s)) without libm tanhf:
//   t = e^{2s};  tanh(s) = (t-1)/(t+1);  two v_exp_f32 + one v_rcp_f32.
// s clamped to +-15 so t stays finite (tanh(15)==1 in fp32 anyway).
__device__ __forceinline__ float exp_tanh(float s) {
    s = fminf(fmaxf(s, -15.f), 15.f);
    float t  = __expf(2.0f * s);
    float th = (t - 1.0f) * __builtin_amdgcn_rcpf(t + 1.0f);
    return __expf(th);
}

// ---------------------------------------------------------------------------
// FUSED kernel: R3's pass1 (best measured structure: 2 rows per wave-iter,
// interleaved 8-row block window, plain float4 loads, compiler-scheduled)
// + last-block-per-batch finalize (canonical threadfence reduction, as in
// rocPRIM deviceReduce — valid across XCDs: release fence flushes producer
// L2, device-scope atomic ticket, acquire fence invalidates consumer L2).
// Eliminates the second dispatch and the inter-kernel gap (~5 us).
//
// Per row: wave-64 dot with register-resident W, shuffle reduce,
// e = exp(tanh(dot+bias)) (tanh bounds scores -> softmax needs no max),
// e stored unnormalized into the weights output, context partial in regs.
// Block epilogue: 4-wave LDS combine -> per-chunk (Z, c[512]) partials.
// Last block of each batch: sum partials, write context, rescale weights.
// ---------------------------------------------------------------------------
__global__ __launch_bounds__(256) void attn_fused(
    const float* __restrict__ x, const float* __restrict__ W,
    const float* __restrict__ bias,
    float* __restrict__ e_out,   // [NB*NS]  (weights region of d_out)
    float* __restrict__ ctx,     // [NB*ND]
    float* __restrict__ Zp,      // [NB*nchunk]
    float* __restrict__ Cp,      // [NB*nchunk*ND]
    int*   __restrict__ cnt,     // [NB] zeroed per launch
    int nchunk, int chunk)
{
    const int b    = blockIdx.y;
    const int ch   = blockIdx.x;
    const int tid  = threadIdx.x;
    const int wv   = tid >> 6;      // 0..3
    const int lane = tid & 63;

    const float4 w1 = *(const float4*)(W + 4 * lane);
    const float4 w2 = *(const float4*)(W + 256 + 4 * lane);

    const float* xb = x + (size_t)b * NS * ND;
    const int row0 = ch * chunk;

    float4 c1 = make_float4(0.f, 0.f, 0.f, 0.f);
    float4 c2 = make_float4(0.f, 0.f, 0.f, 0.f);
    float zacc = 0.f;

    // chunk is a multiple of 8; waves 0..3 each process pairs (r, r+4).
    for (int r = wv; r < chunk; r += 8) {
        const int ia = row0 + r;
        const int ib = ia + 4;
        const float* xra = xb + (size_t)ia * ND;
        const float* xrb = xb + (size_t)ib * ND;
        float4 a1 = *(const float4*)(xra + 4 * lane);
        float4 a2 = *(const float4*)(xra + 256 + 4 * lane);
        float4 b1 = *(const float4*)(xrb + 4 * lane);
        float4 b2 = *(const float4*)(xrb + 256 + 4 * lane);

        float pa = a1.x * w1.x + a1.y * w1.y + a1.z * w1.z + a1.w * w1.w
                 + a2.x * w2.x + a2.y * w2.y + a2.z * w2.z + a2.w * w2.w;
        float pb = b1.x * w1.x + b1.y * w1.y + b1.z * w1.z + b1.w * w1.w
                 + b2.x * w2.x + b2.y * w2.y + b2.z * w2.z + b2.w * w2.w;
        #pragma unroll
        for (int m = 32; m >= 1; m >>= 1) {
            pa += __shfl_xor(pa, m);
            pb += __shfl_xor(pb, m);
        }
        float ea = exp_tanh(pa + bias[ia]);
        float eb = exp_tanh(pb + bias[ib]);
        if (lane == 0) {
            e_out[(size_t)b * NS + ia] = ea;
            e_out[(size_t)b * NS + ib] = eb;
        }
        zacc += ea + eb;
        c1.x += a1.x * ea + b1.x * eb;
        c1.y += a1.y * ea + b1.y * eb;
        c1.z += a1.z * ea + b1.z * eb;
        c1.w += a1.w * ea + b1.w * eb;
        c2.x += a2.x * ea + b2.x * eb;
        c2.y += a2.y * ea + b2.y * eb;
        c2.z += a2.z * ea + b2.z * eb;
        c2.w += a2.w * ea + b2.w * eb;
    }

    // Combine the 4 waves through LDS; write per-chunk partials.
    __shared__ __align__(16) float lc[4][ND];
    __shared__ float lz[4];
    *(float4*)&lc[wv][4 * lane]       = c1;
    *(float4*)&lc[wv][256 + 4 * lane] = c2;
    if (lane == 0) lz[wv] = zacc;
    __syncthreads();

    float* cp = Cp + ((size_t)b * nchunk + ch) * ND;
    for (int d = tid; d < ND; d += 256)
        cp[d] = lc[0][d] + lc[1][d] + lc[2][d] + lc[3][d];
    if (tid == 0)
        Zp[b * nchunk + ch] = lz[0] + lz[1] + lz[2] + lz[3];

    // --- last-block-per-batch finalize (threadfence reduction) ---
    __threadfence();            // release: my partials device-visible
    __syncthreads();            // all threads of this block past their fence
    __shared__ int lastflag;
    if (tid == 0)
        lastflag = (atomicAdd(&cnt[b], 1) == nchunk - 1);
    __syncthreads();
    if (!lastflag) return;
    __threadfence();            // acquire: invalidate stale cached lines

    __shared__ float zsh;
    if (tid < 64) {
        float z = (tid < nchunk) ? Zp[b * nchunk + tid] : 0.f;
        #pragma unroll
        for (int m = 32; m >= 1; m >>= 1) z += __shfl_xor(z, m);
        if (tid == 0) zsh = z;
    }
    __syncthreads();
    const float invZ = 1.0f / zsh;

    // context: 256 threads x 2 dims, coalesced over d.
    const float* cpb = Cp + (size_t)b * nchunk * ND;
    for (int d = tid; d < ND; d += 256) {
        float v = 0.f;
        for (int c = 0; c < nchunk; ++c) v += cpb[(size_t)c * ND + d];
        ctx[b * ND + d] = v * invZ;
    }

    // weights: rescale 4096 floats as float4 (16 per thread).
    float4* wb = (float4*)(e_out + (size_t)b * NS);
    for (int i = tid; i < NS / 4; i += 256) {
        float4 w = wb[i];
        w.x *= invZ; w.y *= invZ; w.z *= invZ; w.w *= invZ;
        wb[i] = w;
    }
}

extern "C" void kernel_launch(void* const* d_in, const int* in_sizes, int n_in,
                              void* d_out, int out_size, void* d_ws, size_t ws_size,
                              hipStream_t stream) {
    const float* x    = (const float*)d_in[0];
    const float* W    = (const float*)d_in[1];
    const float* bias = (const float*)d_in[2];

    float* ctx = (float*)d_out;            // [NB*ND]
    float* wts = ctx + NB * ND;            // [NB*NS]

    // ws layout: [cnt: NB ints][Zp: NB*nchunk][Cp: NB*nchunk*ND]
    int nchunk = 64;
    while (nchunk > 1 &&
           (size_t)4 * (NB + (size_t)NB * nchunk * (1 + ND)) > ws_size)
        nchunk >>= 1;
    const int chunk = NS / nchunk;         // multiple of 8

    int*   cnt = (int*)d_ws;
    float* Zp  = (float*)d_ws + NB;
    float* Cp  = Zp + (size_t)NB * nchunk;

    hipMemsetAsync(cnt, 0, NB * sizeof(int), stream);
    hipLaunchKernelGGL(attn_fused, dim3(nchunk, NB), dim3(256), 0, stream,
                       x, W, bias, wts, ctx, Zp, Cp, cnt, nchunk, chunk);
}

// Round 9
// 51.718 us; speedup vs baseline: 7.2615x; 7.2615x over previous
//
#include <hip/hip_runtime.h>

constexpr int NB = 32;    // batch
constexpr int NS = 4096;  // sequence
constexpr int ND = 512;   // feature dim

// e = exp(tanh(s)) without libm tanhf:
//   t = e^{2s};  tanh(s) = (t-1)/(t+1);  two v_exp_f32 + one v_rcp_f32.
// s clamped to +-15 so t stays finite (tanh(15)==1 in fp32 anyway).
__device__ __forceinline__ float exp_tanh(float s) {
    s = fminf(fmaxf(s, -15.f), 15.f);
    float t  = __expf(2.0f * s);
    float th = (t - 1.0f) * __builtin_amdgcn_rcpf(t + 1.0f);
    return __expf(th);
}

// ---------------------------------------------------------------------------
// FINAL (revert to R3, the best measured configuration: 51.5 us).
// Pass 1: one streaming pass over x.  2 rows per wave-iter, interleaved so
// the block's 4 waves cover 8 consecutive rows per step (compact sliding
// window); compiler-scheduled loop body.  Challengers that lost: 1-row
// high-occupancy (54.1), 4-row unroll (80.4), manual prefetch dbuf (58.0),
// non-temporal loads (53.8), fused single-kernel w/ threadfence (375 — the
// epilogue's fence+atomic path wrecked register allocation: VGPR 32, full
// scratch spill of the hot loop).
// Per row: wave-64 dot with register-resident W, shuffle reduce,
// e = exp(tanh(dot+bias)) (tanh bounds scores -> softmax needs no max),
// e stored unnormalized into the weights output, context partial in regs.
// Epilogue: 4-wave LDS combine -> per-chunk (Z, c[512]).
// ---------------------------------------------------------------------------
__global__ __launch_bounds__(256) void attn_pass1(
    const float* __restrict__ x, const float* __restrict__ W,
    const float* __restrict__ bias,
    float* __restrict__ e_out,   // [NB*NS]   (weights region of d_out)
    float* __restrict__ Zp,      // [NB*nchunk]
    float* __restrict__ Cp,      // [NB*nchunk*ND]
    int nchunk, int chunk)
{
    const int b    = blockIdx.y;
    const int ch   = blockIdx.x;
    const int tid  = threadIdx.x;
    const int wv   = tid >> 6;      // 0..3
    const int lane = tid & 63;

    const float4 w1 = *(const float4*)(W + 4 * lane);
    const float4 w2 = *(const float4*)(W + 256 + 4 * lane);

    const float* xb = x + (size_t)b * NS * ND;
    const int row0 = ch * chunk;

    float4 c1 = make_float4(0.f, 0.f, 0.f, 0.f);
    float4 c2 = make_float4(0.f, 0.f, 0.f, 0.f);
    float zacc = 0.f;

    // chunk is a multiple of 8; waves 0..3 each process pairs (r, r+4).
    for (int r = wv; r < chunk; r += 8) {
        const int ia = row0 + r;
        const int ib = ia + 4;
        const float* xra = xb + (size_t)ia * ND;
        const float* xrb = xb + (size_t)ib * ND;
        float4 a1 = *(const float4*)(xra + 4 * lane);
        float4 a2 = *(const float4*)(xra + 256 + 4 * lane);
        float4 b1 = *(const float4*)(xrb + 4 * lane);
        float4 b2 = *(const float4*)(xrb + 256 + 4 * lane);

        float pa = a1.x * w1.x + a1.y * w1.y + a1.z * w1.z + a1.w * w1.w
                 + a2.x * w2.x + a2.y * w2.y + a2.z * w2.z + a2.w * w2.w;
        float pb = b1.x * w1.x + b1.y * w1.y + b1.z * w1.z + b1.w * w1.w
                 + b2.x * w2.x + b2.y * w2.y + b2.z * w2.z + b2.w * w2.w;
        #pragma unroll
        for (int m = 32; m >= 1; m >>= 1) {
            pa += __shfl_xor(pa, m);
            pb += __shfl_xor(pb, m);
        }
        float ea = exp_tanh(pa + bias[ia]);
        float eb = exp_tanh(pb + bias[ib]);
        if (lane == 0) {
            e_out[(size_t)b * NS + ia] = ea;
            e_out[(size_t)b * NS + ib] = eb;
        }
        zacc += ea + eb;
        c1.x += a1.x * ea + b1.x * eb;
        c1.y += a1.y * ea + b1.y * eb;
        c1.z += a1.z * ea + b1.z * eb;
        c1.w += a1.w * ea + b1.w * eb;
        c2.x += a2.x * ea + b2.x * eb;
        c2.y += a2.y * ea + b2.y * eb;
        c2.z += a2.z * ea + b2.z * eb;
        c2.w += a2.w * ea + b2.w * eb;
    }

    // Combine the 4 waves through LDS.
    __shared__ __align__(16) float lc[4][ND];
    __shared__ float lz[4];
    *(float4*)&lc[wv][4 * lane]       = c1;
    *(float4*)&lc[wv][256 + 4 * lane] = c2;
    if (lane == 0) lz[wv] = zacc;
    __syncthreads();

    float* cp = Cp + ((size_t)b * nchunk + ch) * ND;
    for (int d = tid; d < ND; d += 256)
        cp[d] = lc[0][d] + lc[1][d] + lc[2][d] + lc[3][d];
    if (tid == 0)
        Zp[b * nchunk + ch] = lz[0] + lz[1] + lz[2] + lz[3];
}

// ---------------------------------------------------------------------------
// Pass 2: finalize.  Grid: (NB, 8) x 256 threads — whole machine
// participates.  Every block redundantly computes Z for its batch (cheap);
// block (b, j) writes context dims [j*64, j*64+64) and rescales weights
// [j*512, j*512+512).
// ---------------------------------------------------------------------------
__global__ __launch_bounds__(256) void attn_pass2(
    const float* __restrict__ Zp, const float* __restrict__ Cp,
    float* __restrict__ w_inout,   // [NB*NS]
    float* __restrict__ ctx,       // [NB*ND]
    int nchunk)
{
    const int b = blockIdx.x;
    const int j = blockIdx.y;
    const int t = threadIdx.x;

    __shared__ float zs;
    __shared__ float lc[4][64];

    if (t < 64) {
        float z = (t < nchunk) ? Zp[b * nchunk + t] : 0.f;
        #pragma unroll
        for (int m = 32; m >= 1; m >>= 1) z += __shfl_xor(z, m);
        if (t == 0) zs = z;
    }
    __syncthreads();
    const float invZ = 1.0f / zs;

    // context slice: 4 chunk-groups x 64 dims, coalesced over d.
    const int cg = t >> 6;          // 0..3
    const int dl = t & 63;
    const int d  = j * 64 + dl;
    const float* cpb = Cp + (size_t)b * nchunk * ND;
    float v = 0.f;
    for (int c = cg; c < nchunk; c += 4)
        v += cpb[(size_t)c * ND + d];
    lc[cg][dl] = v;
    __syncthreads();
    if (t < 64)
        ctx[b * ND + j * 64 + t] = (lc[0][t] + lc[1][t] + lc[2][t] + lc[3][t]) * invZ;

    // weights slice: 512 elements as float2 per thread.
    float2* wb = (float2*)(w_inout + (size_t)b * NS + j * 512);
    float2 w = wb[t];
    w.x *= invZ; w.y *= invZ;
    wb[t] = w;
}

extern "C" void kernel_launch(void* const* d_in, const int* in_sizes, int n_in,
                              void* d_out, int out_size, void* d_ws, size_t ws_size,
                              hipStream_t stream) {
    const float* x    = (const float*)d_in[0];
    const float* W    = (const float*)d_in[1];
    const float* bias = (const float*)d_in[2];

    float* ctx = (float*)d_out;            // [NB*ND]
    float* wts = ctx + NB * ND;            // [NB*NS]

    // Largest chunk count whose partials fit the workspace (<=64 so the
    // pass-2 wave reduce covers it; chunk stays a multiple of 8).
    int nchunk = 64;
    while (nchunk > 1 &&
           (size_t)4 * NB * nchunk * (1 + ND) > ws_size)
        nchunk >>= 1;
    const int chunk = NS / nchunk;         // multiple of 8

    float* Zp = (float*)d_ws;
    float* Cp = Zp + (size_t)NB * nchunk;

    hipLaunchKernelGGL(attn_pass1, dim3(nchunk, NB), dim3(256), 0, stream,
                       x, W, bias, wts, Zp, Cp, nchunk, chunk);
    hipLaunchKernelGGL(attn_pass2, dim3(NB, 8), dim3(256), 0, stream,
                       Zp, Cp, wts, ctx, nchunk);
}